// Round 8
// baseline (157.276 us; speedup 1.0000x reference)
//
#include <hip/hip_runtime.h>

// B=16, C=3, H=256, W=256 fp32. 48 slices of 256x256.
// out = inverted, per-slice max-normalized, per-channel-weighted exact EDT.
//
// ONE compute kernel (plus a 1KB hipMemsetAsync for ctrl), 768 blocks x 256.
// Co-residency guaranteed arithmetically: grid 768 = 256 CU x 3;
// LDS 18.5 KB -> 8 blk/CU; __launch_bounds__(256,3) -> VGPR<=170 -> 3 blk/CU.
// Block bx -> (slice, strip) XCD-chunked: slice=(bx&7)*6+((bx>>3)>>4),
// strip=(bx>>3)&15  => a slice's 16 strips live on one XCD's L2 (perf only).
//
//   Phase 1: block computes g (1D nearest-zero dist) for its slice's rows
//            strip*16..+15 in ballot registers, writes u16 g; fence +
//            per-slice counter; thread0 spins until 16 posted (~us: uniform
//            work, all blocks resident from t=0).
//   Phase 2: g slice-strip -> LDS tile (d^2 float, col-major stride 289, 16
//            pad rows/side); own[16] in regs; +-16 paired window min-plus;
//            EXACT fallback (full-column rescan in LDS) when windowed
//            min > 288 (|o|>=17 candidates >= 289).
//   Spill-to-LDS (the R1/R7 remat fix): tile is dead after fallback ->
//            overwrite with dmin BEFORE the slice-max spin, so nothing big
//            is live across the wait and hipcc can't re-run the window pass.
//   Phase 3: block max -> atomicMax(ctrl[slice]) -> fence -> counter ->
//            spin -> epilogue out = (mx - w*sqrt(d2))/mx reading dmin from LDS.

#define PADV 1e30f

__global__ __launch_bounds__(256, 3)
void kfused(const float* __restrict__ in, float* __restrict__ out,
            unsigned short* __restrict__ g, unsigned* __restrict__ ctrl) {
    __shared__ float tile[16 * 289];   // 18496 B
    __shared__ float wm[4];
    __shared__ float sMx;

    int bx = blockIdx.x;               // 0..767
    int tid = threadIdx.x;
    int lane = tid & 63;
    int wv = tid >> 6;                 // wave 0..3

    int slice = (bx & 7) * 6 + ((bx >> 3) >> 4);   // 0..47 (XCD-chunked)
    int strip = (bx >> 3) & 15;                    // 0..15
    int w0 = strip * 16;

    // ---------------- phase 1: g16 via ballots, 4 rows per wave -------------
    // Lane l holds cols 4l..4l+3. b[cc] bit j = (col 4j+cc == 0).
    {
        unsigned long long loP = ~0ull >> (63 - lane);  // bits 0..lane
        unsigned long long loM = loP >> 1;              // bits 0..lane-1
        unsigned long long hiP = ~0ull << lane;         // bits lane..63
        unsigned long long hiM = hiP << 1;              // bits lane+1..63
        #pragma unroll
        for (int i = 0; i < 4; ++i) {
            int row = slice * 256 + strip * 16 + wv * 4 + i;
            const float4 m = ((const float4*)in)[(long)row * 64 + lane];
            unsigned long long b[4];
            b[0] = __ballot(m.x == 0.f);
            b[1] = __ballot(m.y == 0.f);
            b[2] = __ballot(m.z == 0.f);
            b[3] = __ballot(m.w == 0.f);

            int LP[4], LM[4], RP[4], RM[4];
            #pragma unroll
            for (int cc = 0; cc < 4; ++cc) {
                unsigned long long mlp = b[cc] & loP;
                unsigned long long mlm = b[cc] & loM;
                unsigned long long mhp = b[cc] & hiP;
                unsigned long long mhm = b[cc] & hiM;
                LP[cc] = mlp ? 4 * (63 - __builtin_clzll(mlp)) + cc : -1000;
                LM[cc] = mlm ? 4 * (63 - __builtin_clzll(mlm)) + cc : -1000;
                RP[cc] = mhp ? 4 * __builtin_ctzll(mhp) + cc : 2000;
                RM[cc] = mhm ? 4 * __builtin_ctzll(mhm) + cc : 2000;
            }
            // colL(ci) = max( LP[cc] for cc<=ci, LM[cc] for cc>ci )
            int qp1 = max(LP[0], LP[1]);
            int qp2 = max(qp1, LP[2]);
            int qp3 = max(qp2, LP[3]);
            int sm3 = LM[3];
            int sm2 = max(LM[2], sm3);
            int sm1 = max(LM[1], sm2);
            int colL0 = max(LP[0], sm1);
            int colL1 = max(qp1, sm2);
            int colL2 = max(qp2, sm3);
            int colL3 = qp3;
            // colR(ci) = min( RM[cc] for cc<ci, RP[cc] for cc>=ci )
            int sp2 = min(RP[2], RP[3]);
            int sp1 = min(RP[1], sp2);
            int sp0 = min(RP[0], sp1);
            int pm0 = RM[0];
            int pm1 = min(pm0, RM[1]);
            int pm2 = min(pm1, RM[2]);
            int colR0 = sp0;
            int colR1 = min(pm0, sp1);
            int colR2 = min(pm1, sp2);
            int colR3 = min(pm2, RP[3]);

            int p0 = lane * 4;
            int d0 = min(min(p0 - colL0, colR0 - p0), 512);        // cap = BIG
            int d1 = min(min(p0 + 1 - colL1, colR1 - p0 - 1), 512);
            int d2 = min(min(p0 + 2 - colL2, colR2 - p0 - 2), 512);
            int d3 = min(min(p0 + 3 - colL3, colR3 - p0 - 3), 512);

            ushort4 v;
            v.x = (unsigned short)d0; v.y = (unsigned short)d1;
            v.z = (unsigned short)d2; v.w = (unsigned short)d3;
            ((ushort4*)(g + (long)row * 256))[lane] = v;           // coalesced
        }
    }
    __syncthreads();                   // drain this block's g stores (vmcnt)
    if (tid == 0) {
        __threadfence();               // publish g (agent-scope wb)
        atomicAdd(ctrl + 128 + slice, 1u);
        while (__hip_atomic_load(ctrl + 128 + slice, __ATOMIC_RELAXED,
                                 __HIP_MEMORY_SCOPE_AGENT) < 16u) {
            __builtin_amdgcn_s_sleep(2);
        }
        __threadfence();               // acquire (inv) before reading g
    }
    __syncthreads();

    // ---------------- phase 2: column min-plus for (slice, strip) -----------
    // fill tile: idx 0..287 <-> row idx-16 (u16 d -> float d^2 on the fly)
    #pragma unroll
    for (int pass = 0; pass < 2; ++pass) {
        int idx = pass * 256 + tid;
        if (pass == 0 || tid < 32) {
            int r = idx - 16;
            if (r >= 0 && r < 256) {
                const uint4* src = (const uint4*)(g + (long)slice * 65536 + (long)r * 256 + w0);
                #pragma unroll
                for (int j = 0; j < 2; ++j) {
                    uint4 q = src[j];
                    unsigned vv[4] = {q.x, q.y, q.z, q.w};
                    #pragma unroll
                    for (int e = 0; e < 4; ++e) {
                        float dl = (float)(vv[e] & 0xffffu);
                        float dh = (float)(vv[e] >> 16);
                        int col = j * 8 + e * 2;
                        tile[col * 289 + idx] = dl * dl;     // <=2-way banking
                        tile[(col + 1) * 289 + idx] = dh * dh;
                    }
                }
            } else {
                #pragma unroll
                for (int cc = 0; cc < 16; ++cc) tile[cc * 289 + idx] = PADV;
            }
        }
    }
    __syncthreads();

    int c = tid & 15;                  // column within strip
    int rg = tid >> 4;                 // 0..15
    int r0 = rg * 16;                  // owned rows r0..r0+15
    int i0 = 16 + r0;                  // tile index of first owned row

    float own[16], lo[16], hi[16];
    #pragma unroll
    for (int k = 0; k < 16; ++k) own[k] = tile[c * 289 + i0 + k];
    #pragma unroll
    for (int i = 0; i < 16; ++i) {
        lo[i] = tile[c * 289 + i0 - 16 + i];   // rows r0-16..r0-1 (pads rg==0)
        hi[i] = tile[c * 289 + i0 + 16 + i];   // rows r0+16..r0+31 (pads rg==15)
    }

    // window min-plus, +-o paired: min(s[k-o], s[k+o]) + o^2
    float dmin[16];
    #pragma unroll
    for (int k = 0; k < 16; ++k) dmin[k] = own[k];
    #pragma unroll
    for (int o = 1; o <= 16; ++o) {
        float oo = (float)(o * o);
        #pragma unroll
        for (int k = 0; k < 16; ++k) {
            int jm = k - o, jp = k + o;
            float a = (jm >= 0) ? own[jm] : lo[jm + 16];
            float b = (jp < 16) ? own[jp] : hi[jp - 16];
            dmin[k] = fminf(dmin[k], fminf(a, b) + oo);
        }
    }

    // exact fallback: windowed min > 288 can't certify +-16 optimality;
    // rescan the full column (in LDS). Never taken for random masks (execz).
    #pragma unroll
    for (int k = 0; k < 16; ++k) {
        if (dmin[k] > 288.0f) {
            float best = dmin[k];
            int r = r0 + k;
            for (int rp = 0; rp < 256; ++rp) {
                float dr = (float)(r - rp);
                best = fminf(best, fmaf(dr, dr, tile[c * 289 + 16 + rp]));
            }
            dmin[k] = best;
        }
    }
    __syncthreads();                   // all g^2 reads done: tile reusable

    // spill dmin -> tile (the remat fix: nothing big lives across the spin)
    float mmax = 0.f;
    #pragma unroll
    for (int k = 0; k < 16; ++k) {
        tile[c * 289 + i0 + k] = dmin[k];
        mmax = fmaxf(mmax, dmin[k]);
    }

    // block max -> slice max via device-scope atomics; spin until 16 strips
    #pragma unroll
    for (int off = 32; off >= 1; off >>= 1)
        mmax = fmaxf(mmax, __shfl_down(mmax, off, 64));
    if ((tid & 63) == 0) wm[tid >> 6] = mmax;
    __syncthreads();
    if (tid == 0) {
        float bmax = fmaxf(fmaxf(wm[0], wm[1]), fmaxf(wm[2], wm[3]));
        atomicMax(ctrl + slice, __float_as_uint(bmax));   // d2>=0: order-safe
        __threadfence();
        atomicAdd(ctrl + 64 + slice, 1u);
        while (__hip_atomic_load(ctrl + 64 + slice, __ATOMIC_RELAXED,
                                 __HIP_MEMORY_SCOPE_AGENT) < 16u) {
            __builtin_amdgcn_s_sleep(2);
        }
        sMx = __uint_as_float(__hip_atomic_load(ctrl + slice, __ATOMIC_RELAXED,
                                                __HIP_MEMORY_SCOPE_AGENT));
    }
    __syncthreads();

    // ---------------- phase 3: epilogue, dmin read back from LDS ------------
    int ch = slice % 3;
    float wgt = (ch == 0) ? 0.5f : ((ch == 1) ? 1.0f : 2.0f);
    float mx = wgt * __builtin_sqrtf(sMx);
    float* dst = out + (long)slice * 65536 + w0 + c;
    if (mx > 0.f) {
        float inv = 1.0f / mx;
        #pragma unroll
        for (int k = 0; k < 16; ++k) {
            float d2v = tile[c * 289 + i0 + k];
            dst[(long)(r0 + k) * 256] = (mx - wgt * __builtin_sqrtf(d2v)) * inv;
        }
    } else {
        #pragma unroll
        for (int k = 0; k < 16; ++k) {
            float d2v = tile[c * 289 + i0 + k];
            dst[(long)(r0 + k) * 256] = wgt * __builtin_sqrtf(d2v);
        }
    }
}

extern "C" void kernel_launch(void* const* d_in, const int* in_sizes, int n_in,
                              void* d_out, int out_size, void* d_ws, size_t ws_size,
                              hipStream_t stream) {
    const float* in = (const float*)d_in[0];
    float* out = (float*)d_out;
    unsigned* ctrl = (unsigned*)d_ws;                                  // 256 uints
    unsigned short* g = (unsigned short*)((char*)d_ws + 4096);         // 6.29 MB

    hipMemsetAsync(ctrl, 0, 1024, stream);                // zero ctrl (capturable)
    kfused<<<768, 256, 0, stream>>>(in, out, g, ctrl);
}

// Round 9
// 81.727 us; speedup vs baseline: 1.9244x; 1.9244x over previous
//
#include <hip/hip_runtime.h>

// B=16, C=3, H=256, W=256 fp32. 48 slices of 256x256.
// out = inverted, per-slice max-normalized, per-channel-weighted exact EDT.
//
// Pipeline (3 launches; kernel boundaries are the ONLY global sync — measured:
// atomic-spin barrier ~50us, cooperative grid.sync ~120us, boundary ~3us):
//   K1: wave per row. Ballots give every lane the full 256-col zero-mask in 4
//       ulls; each lane computes EXACT 1D nearest-zero distance for its 4 cols
//       in registers (residue unroll + prefix max/min), writes g u16 row-major.
//   K2: quarter-slice column tiles: 48 slices x 16 col-strips x 4 row-quarters
//       = 3072 blocks (12 waves/SIMD). g tile (96 rows x 16 cols, +-16 halo)
//       -> LDS as d^2 f32 (col-major stride 101); own[4] rows in regs; +-16
//       paired window min-plus; EXACT fallback (full 256-row column rescan
//       from global g) when windowed min > 288 (|o|>=17 candidates >= 289;
//       never taken for random masks -> execz). d2 -> out, block max -> ws.
//   K3: 1536 blocks; slice max = wave-reduce of 64 block maxes; epilogue
//       out = (mx - w*sqrt(d2))/mx, 2 float4 per thread.

#define PADV 1e30f

// ---------------- K1: register 1D EDT via ballots ---------------------------
// Lane l holds cols 4l..4l+3. b[cc] bit j = (col 4j+cc == 0).
// Left target for col p=4l+ci, residue cc: j <= l - (ci<cc); right: j >= l + (ci>cc).
__global__ __launch_bounds__(256) void k1_g16(const float* __restrict__ in,
                                              unsigned short* __restrict__ g) {
    int row = blockIdx.x * 4 + (threadIdx.x >> 6);
    int lane = threadIdx.x & 63;
    const float4 m = ((const float4*)in)[(long)row * 64 + lane];

    unsigned long long b[4];
    b[0] = __ballot(m.x == 0.f);
    b[1] = __ballot(m.y == 0.f);
    b[2] = __ballot(m.z == 0.f);
    b[3] = __ballot(m.w == 0.f);

    unsigned long long loP = ~0ull >> (63 - lane);  // bits 0..lane
    unsigned long long loM = loP >> 1;              // bits 0..lane-1 (0 if lane==0)
    unsigned long long hiP = ~0ull << lane;         // bits lane..63
    unsigned long long hiM = hiP << 1;              // bits lane+1..63 (0 if lane==63)

    int LP[4], LM[4], RP[4], RM[4];
    #pragma unroll
    for (int cc = 0; cc < 4; ++cc) {
        unsigned long long mlp = b[cc] & loP;
        unsigned long long mlm = b[cc] & loM;
        unsigned long long mhp = b[cc] & hiP;
        unsigned long long mhm = b[cc] & hiM;
        LP[cc] = mlp ? 4 * (63 - __builtin_clzll(mlp)) + cc : -1000;  // nearest-left zero col
        LM[cc] = mlm ? 4 * (63 - __builtin_clzll(mlm)) + cc : -1000;
        RP[cc] = mhp ? 4 * __builtin_ctzll(mhp) + cc : 2000;          // nearest-right zero col
        RM[cc] = mhm ? 4 * __builtin_ctzll(mhm) + cc : 2000;
    }
    // colL(ci) = max( LP[cc] for cc<=ci, LM[cc] for cc>ci )
    int qp1 = max(LP[0], LP[1]);
    int qp2 = max(qp1, LP[2]);
    int qp3 = max(qp2, LP[3]);
    int sm3 = LM[3];
    int sm2 = max(LM[2], sm3);
    int sm1 = max(LM[1], sm2);
    int colL0 = max(LP[0], sm1);
    int colL1 = max(qp1, sm2);
    int colL2 = max(qp2, sm3);
    int colL3 = qp3;
    // colR(ci) = min( RM[cc] for cc<ci, RP[cc] for cc>=ci )
    int sp2 = min(RP[2], RP[3]);
    int sp1 = min(RP[1], sp2);
    int sp0 = min(RP[0], sp1);
    int pm0 = RM[0];
    int pm1 = min(pm0, RM[1]);
    int pm2 = min(pm1, RM[2]);
    int colR0 = sp0;
    int colR1 = min(pm0, sp1);
    int colR2 = min(pm1, sp2);
    int colR3 = min(pm2, RP[3]);

    int p0 = lane * 4;
    int d0 = min(min(p0 - colL0, colR0 - p0), 512);          // cap = BIG = H+W
    int d1 = min(min(p0 + 1 - colL1, colR1 - p0 - 1), 512);
    int d2 = min(min(p0 + 2 - colL2, colR2 - p0 - 2), 512);
    int d3 = min(min(p0 + 3 - colL3, colR3 - p0 - 3), 512);

    ushort4 v;
    v.x = (unsigned short)d0; v.y = (unsigned short)d1;
    v.z = (unsigned short)d2; v.w = (unsigned short)d3;
    ((ushort4*)(g + (long)row * 256))[lane] = v;             // coalesced 512 B/wave
}

// ---------------- K2: quarter-slice column min-plus -------------------------
// Grid 3072 = 48 slices x 16 strips x 4 quarters. 256 threads.
// Tile: [16 cols][stride 101], rows 0..95 <-> global rows base-16..base+79.
__global__ __launch_bounds__(256) __attribute__((amdgpu_waves_per_eu(4)))
void k2_colpass(const unsigned short* __restrict__ g,
                float* __restrict__ d2out,
                float* __restrict__ stripmax) {
    __shared__ float tile[16 * 101];   // 6464 B
    __shared__ float wm[4];
    int bx = blockIdx.x;
    int slice = bx >> 6;
    int sub = bx & 63;
    int strip = sub >> 2;
    int quarter = sub & 3;
    int w0 = strip * 16;
    int base = quarter * 64;
    int tid = threadIdx.x;

    // fill: 192 threads, one uint4 (8 u16 = half a tile row) each
    if (tid < 192) {
        int idx = tid >> 1;            // tile row 0..95
        int half = tid & 1;
        int colbase = half * 8;
        int r = base - 16 + idx;
        if (r >= 0 && r < 256) {
            uint4 q = *(const uint4*)(g + (long)slice * 65536 + (long)r * 256 + w0 + colbase);
            unsigned vv[4] = {q.x, q.y, q.z, q.w};
            #pragma unroll
            for (int e = 0; e < 4; ++e) {
                float dl = (float)(vv[e] & 0xffffu);
                float dh = (float)(vv[e] >> 16);
                tile[(colbase + 2 * e) * 101 + idx] = dl * dl;
                tile[(colbase + 2 * e + 1) * 101 + idx] = dh * dh;
            }
        } else {
            #pragma unroll
            for (int e = 0; e < 8; ++e) tile[(colbase + e) * 101 + idx] = PADV;
        }
    }
    __syncthreads();

    int c = tid & 15;                  // column within strip
    int rg = tid >> 4;                 // 0..15
    int i0 = 16 + rg * 4;              // tile row of first owned row

    float own[4], lo[16], hi[16];
    #pragma unroll
    for (int k = 0; k < 4; ++k) own[k] = tile[c * 101 + i0 + k];
    #pragma unroll
    for (int i = 0; i < 16; ++i) {
        lo[i] = tile[c * 101 + i0 - 16 + i];   // rows r0-16..r0-1
        hi[i] = tile[c * 101 + i0 + 4 + i];    // rows r0+4..r0+19
    }

    // window min-plus, +-o paired: min(s[k-o], s[k+o]) + o^2
    float dmin[4];
    #pragma unroll
    for (int k = 0; k < 4; ++k) dmin[k] = own[k];
    #pragma unroll
    for (int o = 1; o <= 16; ++o) {
        float oo = (float)(o * o);
        #pragma unroll
        for (int k = 0; k < 4; ++k) {
            int jm = k - o, jp = k + o;
            float a = (jm >= 0) ? own[jm] : lo[jm + 16];
            float b = (jp < 4) ? own[jp] : hi[jp - 4];
            dmin[k] = fminf(dmin[k], fminf(a, b) + oo);
        }
    }

    int p = w0 + c;
    int r0 = base + rg * 4;
    // exact fallback: windowed min > 288 can't certify +-16 optimality;
    // rescan the full column from global g. Never taken for random masks.
    #pragma unroll
    for (int k = 0; k < 4; ++k) {
        if (dmin[k] > 288.0f) {
            float best = dmin[k];
            int r = r0 + k;
            const unsigned short* col = g + (long)slice * 65536 + p;
            for (int rp = 0; rp < 256; ++rp) {
                float gv = (float)col[rp * 256];
                float dr = (float)(r - rp);
                best = fminf(best, fmaf(dr, dr, gv * gv));
            }
            dmin[k] = best;
        }
    }

    // write d2 + block max
    float* dst = d2out + (long)slice * 65536 + w0 + c;
    float mmax = 0.f;
    #pragma unroll
    for (int k = 0; k < 4; ++k) {
        dst[(long)(r0 + k) * 256] = dmin[k];
        mmax = fmaxf(mmax, dmin[k]);
    }
    #pragma unroll
    for (int off = 32; off >= 1; off >>= 1)
        mmax = fmaxf(mmax, __shfl_down(mmax, off, 64));
    if ((tid & 63) == 0) wm[tid >> 6] = mmax;
    __syncthreads();
    if (tid == 0)
        stripmax[bx] = fmaxf(fmaxf(wm[0], wm[1]), fmaxf(wm[2], wm[3]));
}

// ---------------- K3: epilogue ---------------------------------------------
// 1536 blocks = 32 per slice; each thread handles 2 float4s.
__global__ __launch_bounds__(256) void k3_final(float* __restrict__ out,
                                                const float* __restrict__ stripmax) {
    __shared__ float sMx;
    int tid = threadIdx.x;
    int slice = blockIdx.x >> 5;          // 32 blocks per slice
    if (tid < 64) {
        float v = stripmax[slice * 64 + tid];
        #pragma unroll
        for (int off = 32; off >= 1; off >>= 1) v = fmaxf(v, __shfl_down(v, off, 64));
        if (tid == 0) sMx = v;
    }
    __syncthreads();

    int ch = slice % 3;
    float wgt = (ch == 0) ? 0.5f : ((ch == 1) ? 1.0f : 2.0f);
    float mx = wgt * __builtin_sqrtf(sMx);

    int idx4 = blockIdx.x * 512 + tid;    // float4 index; this + idx4+256
    float4* o4 = (float4*)out;
    #pragma unroll
    for (int rep = 0; rep < 2; ++rep) {
        int i4 = idx4 + rep * 256;
        float4 d2 = o4[i4];
        float4 r;
        if (mx > 0.f) {
            float inv = 1.0f / mx;
            r.x = (mx - wgt * __builtin_sqrtf(d2.x)) * inv;
            r.y = (mx - wgt * __builtin_sqrtf(d2.y)) * inv;
            r.z = (mx - wgt * __builtin_sqrtf(d2.z)) * inv;
            r.w = (mx - wgt * __builtin_sqrtf(d2.w)) * inv;
        } else {
            r.x = wgt * __builtin_sqrtf(d2.x);
            r.y = wgt * __builtin_sqrtf(d2.y);
            r.z = wgt * __builtin_sqrtf(d2.z);
            r.w = wgt * __builtin_sqrtf(d2.w);
        }
        o4[i4] = r;
    }
}

extern "C" void kernel_launch(void* const* d_in, const int* in_sizes, int n_in,
                              void* d_out, int out_size, void* d_ws, size_t ws_size,
                              hipStream_t stream) {
    const float* in = (const float*)d_in[0];
    float* out = (float*)d_out;
    float* stripmax = (float*)d_ws;                                   // 3072 floats
    unsigned short* g = (unsigned short*)((char*)d_ws + 16384);       // 6.29 MB

    k1_g16<<<3072, 256, 0, stream>>>(in, g);              // 12288 rows, wave/row
    k2_colpass<<<3072, 256, 0, stream>>>(g, out, stripmax);
    k3_final<<<1536, 256, 0, stream>>>(out, stripmax);    // 2 float4 / thread
}